// Round 5
// baseline (266.455 us; speedup 1.0000x reference)
//
#include <hip/hip_runtime.h>
#include <hip/hip_bf16.h>
#include <hip/hip_fp16.h>

#define FD 128
#define CBW 64            // coarse bucket width: bucket = dst >> 6
#define NB_MAX 1024

typedef _Float16 half8 __attribute__((ext_vector_type(8)));
typedef float f32x4 __attribute__((ext_vector_type(4)));

// ---------------- coarse histogram (LDS-aggregated) ----------------
__global__ __launch_bounds__(256) void k_chist(const int* __restrict__ dst,
                                               int* __restrict__ ccnt, int e, int nb) {
    __shared__ int lh[NB_MAX];
    for (int i = threadIdx.x; i < nb; i += 256) lh[i] = 0;
    __syncthreads();
    for (int i = blockIdx.x * 256 + threadIdx.x; i < e; i += gridDim.x * 256)
        atomicAdd(&lh[dst[i] >> 6], 1);
    __syncthreads();
    for (int i = threadIdx.x; i < nb; i += 256) {
        int c = lh[i];
        if (c) atomicAdd(&ccnt[i], c);
    }
}

// ---------------- scan of coarse counts (single block) ----------------
__global__ void k_cscan(const int* __restrict__ ccnt, int* __restrict__ cbase,
                        int* __restrict__ ccur, int nb, int* __restrict__ rowptr, int n) {
    __shared__ int wsum[16];
    __shared__ int woff[17];
    const int t = threadIdx.x, lane = t & 63, wid = t >> 6;
    int carry = 0;
    for (int base = 0; base < nb; base += 1024) {
        int idx = base + t;
        int v = (idx < nb) ? ccnt[idx] : 0;
        int s = v;
#pragma unroll
        for (int off = 1; off < 64; off <<= 1) {
            int u = __shfl_up(s, off, 64);
            if (lane >= off) s += u;
        }
        if (lane == 63) wsum[wid] = s;
        __syncthreads();
        if (wid == 0) {
            int w2 = (lane < 16) ? wsum[lane] : 0;
#pragma unroll
            for (int off = 1; off < 16; off <<= 1) {
                int u = __shfl_up(w2, off, 64);
                if (lane >= off) w2 += u;
            }
            if (lane < 16) woff[lane + 1] = w2;
            if (lane == 0) woff[0] = 0;
        }
        __syncthreads();
        int excl = carry + woff[wid] + (s - v);
        if (idx < nb) { cbase[idx] = excl; ccur[idx] = excl; }
        carry += woff[16];
        __syncthreads();
    }
    if (t == 0) { cbase[nb] = carry; rowptr[n] = carry; }
}

// ---------------- coarse scatter: pack (src<<6 | dst&63) into bucket-major ebuf ----------------
__global__ __launch_bounds__(256) void k_cscatter(const int* __restrict__ src,
                                                  const int* __restrict__ dst,
                                                  int* __restrict__ ccur,
                                                  int* __restrict__ ebuf,
                                                  int e, int nb, int nblocks) {
    __shared__ int lh[NB_MAX];
    __shared__ int lb[NB_MAX];
    const int per = (e + nblocks - 1) / nblocks;
    const int lo = blockIdx.x * per;
    const int hi = min(e, lo + per);
    const int t = threadIdx.x;
    for (int i = t; i < nb; i += 256) lh[i] = 0;
    __syncthreads();
    for (int i = lo + t; i < hi; i += 256) atomicAdd(&lh[dst[i] >> 6], 1);
    __syncthreads();
    for (int i = t; i < nb; i += 256) {
        int c = lh[i];
        lb[i] = c ? atomicAdd(&ccur[i], c) : 0;
    }
    __syncthreads();
    for (int i = t; i < nb; i += 256) lh[i] = 0;
    __syncthreads();
    for (int i = lo + t; i < hi; i += 256) {
        int d = dst[i];
        int bkt = d >> 6;
        int r = atomicAdd(&lh[bkt], 1);
        ebuf[lb[bkt] + r] = (src[i] << 6) | (d & (CBW - 1));
    }
}

// ---------------- fine counting sort within each coarse bucket ----------------
__global__ __launch_bounds__(256) void k_fine(const int* __restrict__ ebuf,
                                              const int* __restrict__ cbase,
                                              int* __restrict__ rowptr,
                                              int* __restrict__ colidx, int n) {
    const int b = blockIdx.x;
    const int node0 = b * CBW;
    const int nloc = min(CBW, n - node0);
    const int beg = cbase[b], end = cbase[b + 1];
    __shared__ int fh[CBW];
    __shared__ int fo[CBW];
    const int t = threadIdx.x;
    if (t < CBW) fh[t] = 0;
    __syncthreads();
    for (int e = beg + t; e < end; e += 256) atomicAdd(&fh[ebuf[e] & (CBW - 1)], 1);
    __syncthreads();
    if (t < 64) {
        int v = fh[t];
        int s = v;
#pragma unroll
        for (int off = 1; off < 64; off <<= 1) {
            int u = __shfl_up(s, off, 64);
            if (t >= off) s += u;
        }
        fo[t] = s - v;
    }
    __syncthreads();
    if (t < nloc) rowptr[node0 + t] = beg + fo[t];
    if (t < CBW) fh[t] = 0;
    __syncthreads();
    for (int e = beg + t; e < end; e += 256) {
        int v = ebuf[e];
        int d = v & (CBW - 1);
        int r = atomicAdd(&fh[d], 1);
        colidx[beg + fo[d] + r] = v >> 6;
    }
}

// ---------------- W -> W^T fp16 ----------------
__global__ __launch_bounds__(1024) void k_wt(const float* __restrict__ Wa,
                                             const float* __restrict__ Wb,
                                             __half* __restrict__ Ta,
                                             __half* __restrict__ Tb) {
    __shared__ float sw[128 * 129];
    const float* W = blockIdx.x ? Wb : Wa;
    __half* T = blockIdx.x ? Tb : Ta;
    const int t = threadIdx.x;
#pragma unroll
    for (int i = 0; i < 16; i++) {
        int idx = i * 1024 + t;
        sw[(idx >> 7) * 129 + (idx & 127)] = W[idx];
    }
    __syncthreads();
#pragma unroll
    for (int i = 0; i < 8; i++) {
        int o = i * 1024 + t;
        int c = o >> 6, kp = o & 63;
        float lo = sw[(kp * 2) * 129 + c];
        float hi = sw[(kp * 2 + 1) * 129 + c];
        *(__half2*)&T[c * 128 + kp * 2] = __floats2half2_rn(lo, hi);
    }
}

// ---------------- MFMA GEMM: H = X @ W (fp16 in, fp32 acc) + fused dots ----------------
__global__ __launch_bounds__(256) void k_gemm(const float* __restrict__ X,
                                              const __half* __restrict__ Wt,
                                              const float* __restrict__ a_s,
                                              const float* __restrict__ a_d,
                                              __half* __restrict__ H,
                                              float* __restrict__ as_,
                                              float* __restrict__ ad_, int n) {
    const int t = threadIdx.x;
    const int wave = t >> 6, lane = t & 63;
    const int g = lane >> 4, c16 = lane & 15;
    const int row0 = blockIdx.x * 64 + wave * 16;

    half8 A[4];
    {
        int row = row0 + c16;
        int rc = (row < n) ? row : (n - 1);
        const float* xp = &X[(size_t)rc * 128 + g * 8];
#pragma unroll
        for (int kc = 0; kc < 4; kc++) {
            float4 x0 = *(const float4*)(xp + kc * 32);
            float4 x1 = *(const float4*)(xp + kc * 32 + 4);
            half8 a;
            a[0] = (_Float16)x0.x; a[1] = (_Float16)x0.y;
            a[2] = (_Float16)x0.z; a[3] = (_Float16)x0.w;
            a[4] = (_Float16)x1.x; a[5] = (_Float16)x1.y;
            a[6] = (_Float16)x1.z; a[7] = (_Float16)x1.w;
            A[kc] = a;
        }
    }

    f32x4 acc[8];
#pragma unroll
    for (int ct = 0; ct < 8; ct++) acc[ct] = (f32x4){0.f, 0.f, 0.f, 0.f};

#pragma unroll
    for (int ct = 0; ct < 8; ct++) {
        const __half* wp = &Wt[(ct * 16 + c16) * 128 + g * 8];
#pragma unroll
        for (int kc = 0; kc < 4; kc++) {
            half8 b = *(const half8*)(wp + kc * 32);
            acc[ct] = __builtin_amdgcn_mfma_f32_16x16x32_f16(A[kc], b, acc[ct], 0, 0, 0);
        }
    }

    float asv[8], adv[8];
#pragma unroll
    for (int ct = 0; ct < 8; ct++) {
        asv[ct] = a_s[ct * 16 + c16];
        adv[ct] = a_d[ct * 16 + c16];
    }
#pragma unroll
    for (int r = 0; r < 4; r++) {
        const int row = row0 + g * 4 + r;
        float vs = 0.f, vd = 0.f;
#pragma unroll
        for (int ct = 0; ct < 8; ct++) {
            float v = acc[ct][r];
            vs += v * asv[ct];
            vd += v * adv[ct];
            if (row < n) H[(size_t)row * 128 + ct * 16 + c16] = __float2half(v);
        }
#pragma unroll
        for (int off = 8; off; off >>= 1) {
            vs += __shfl_xor(vs, off, 16);
            vd += __shfl_xor(vd, off, 16);
        }
        if (c16 == 0 && row < n) { as_[row] = vs; ad_[row] = vd; }
    }
}

// ---------------- per-edge normalized attention weights (wave per node) ----------------
__global__ __launch_bounds__(256) void k_alpha(const float* __restrict__ as_,
                                               const float* __restrict__ ad_,
                                               const int* __restrict__ rowptr,
                                               const int* __restrict__ colidx,
                                               float* __restrict__ alpha,
                                               float* __restrict__ aself, int n) {
    const int wid = threadIdx.x >> 6;
    const int lane = threadIdx.x & 63;
    const int node = blockIdx.x * 4 + wid;
    if (node >= n) return;
    const float adn = ad_[node];
    const int beg = rowptr[node], end = rowptr[node + 1];
    float s = 0.f;
    for (int i = beg + lane; i < end; i += 64) {
        float e = as_[colidx[i]] + adn;
        e = (e > 0.f) ? e : 0.2f * e;
        float w = __expf(e);
        alpha[i] = w;
        s += w;
    }
    float es = as_[node] + adn;
    es = (es > 0.f) ? es : 0.2f * es;
    const float wself = __expf(es);
    if (lane == 0) s += wself;
#pragma unroll
    for (int off = 32; off; off >>= 1) s += __shfl_xor(s, off);
    const float inv = 1.f / s;
    for (int i = beg + lane; i < end; i += 64) alpha[i] *= inv;
    if (lane == 0) aself[node] = wself * inv;
}

// ---------------- aggregation: out[d] = sum alpha*H[src] + aself*H[d] + b ----------------
__device__ __forceinline__ void fmix8(float* acc, uint4 hv, float w) {
    union { uint4 u; _Float16 h[8]; } c;
    c.u = hv;
#pragma unroll
    for (int j = 0; j < 8; j++) acc[j] += w * (float)c.h[j];
}

__global__ __launch_bounds__(256) void k_aggr(const __half* __restrict__ H,
                                              const float* __restrict__ alpha,
                                              const float* __restrict__ aself,
                                              const int* __restrict__ rowptr,
                                              const int* __restrict__ colidx,
                                              const float* __restrict__ bias,
                                              float* __restrict__ out, int n, int do_relu) {
    const int wid = threadIdx.x >> 6;
    const int lane = threadIdx.x & 63;
    const int node = blockIdx.x * 4 + wid;
    if (node >= n) return;
    const int q = lane >> 4;
    const int l = lane & 15;
    const int f0 = l * 8;
    float acc[8] = {0.f, 0.f, 0.f, 0.f, 0.f, 0.f, 0.f, 0.f};
    const int beg = rowptr[node], end = rowptr[node + 1];

    int i0 = beg + q, i1 = beg + q + 4;
    int s0 = 0, s1 = 0;
    float w0 = 0.f, w1 = 0.f;
    if (i0 < end) { s0 = colidx[i0]; w0 = alpha[i0]; }
    if (i1 < end) { s1 = colidx[i1]; w1 = alpha[i1]; }
    while (i0 < end) {
        const uint4 h0 = *(const uint4*)&H[(size_t)s0 * 128 + f0];
        const bool has1 = (i1 < end);
        uint4 h1;
        if (has1) h1 = *(const uint4*)&H[(size_t)s1 * 128 + f0];
        const float cw0 = w0, cw1 = w1;
        const int n0 = i0 + 8, n1 = i1 + 8;
        if (n0 < end) { s0 = colidx[n0]; w0 = alpha[n0]; }
        if (n1 < end) { s1 = colidx[n1]; w1 = alpha[n1]; }
        fmix8(acc, h0, cw0);
        if (has1) fmix8(acc, h1, cw1);
        i0 = n0; i1 = n1;
    }
    if (q == 3) {   // self loop
        const float w = aself[node];
        const uint4 hv = *(const uint4*)&H[(size_t)node * 128 + f0];
        fmix8(acc, hv, w);
    }
#pragma unroll
    for (int off = 16; off <= 32; off <<= 1) {
#pragma unroll
        for (int j = 0; j < 8; j++) acc[j] += __shfl_xor(acc[j], off);
    }
    if (q == 0) {
        const float4 b0 = *(const float4*)&bias[f0];
        const float4 b1 = *(const float4*)&bias[f0 + 4];
        float4 o0, o1;
        o0.x = acc[0] + b0.x; o0.y = acc[1] + b0.y;
        o0.z = acc[2] + b0.z; o0.w = acc[3] + b0.w;
        o1.x = acc[4] + b1.x; o1.y = acc[5] + b1.y;
        o1.z = acc[6] + b1.z; o1.w = acc[7] + b1.w;
        if (do_relu) {
            o0.x = fmaxf(o0.x, 0.f); o0.y = fmaxf(o0.y, 0.f);
            o0.z = fmaxf(o0.z, 0.f); o0.w = fmaxf(o0.w, 0.f);
            o1.x = fmaxf(o1.x, 0.f); o1.y = fmaxf(o1.y, 0.f);
            o1.z = fmaxf(o1.z, 0.f); o1.w = fmaxf(o1.w, 0.f);
        }
        *(float4*)&out[(size_t)node * 128 + f0] = o0;
        *(float4*)&out[(size_t)node * 128 + f0 + 4] = o1;
    }
}

extern "C" void kernel_launch(void* const* d_in, const int* in_sizes, int n_in,
                              void* d_out, int out_size, void* d_ws, size_t ws_size,
                              hipStream_t stream) {
    const float* x   = (const float*)d_in[0];
    const int*   ei  = (const int*)d_in[1];
    const float* W1  = (const float*)d_in[2];
    const float* a1s = (const float*)d_in[3];
    const float* a1d = (const float*)d_in[4];
    const float* b1  = (const float*)d_in[5];
    const float* W2  = (const float*)d_in[6];
    const float* a2s = (const float*)d_in[7];
    const float* a2d = (const float*)d_in[8];
    const float* b2  = (const float*)d_in[9];
    float* dout = (float*)d_out;

    const int n = in_sizes[0] / FD;          // 50000
    const int E = in_sizes[1] / 2;           // 1600000
    const int* src = ei;
    const int* dst = ei + E;
    const int NB = (n + CBW - 1) / CBW;      // 782 coarse buckets

    // workspace layout (ebuf aliases H: H is dead during CSR build)
    __half* H     = (__half*)d_ws;           // n*128 halves (12.8 MB)
    int*    ebuf  = (int*)d_ws;              // E ints (6.4 MB) — aliases H
    float* as_    = (float*)((char*)d_ws + (size_t)n * FD * sizeof(__half));
    float* ad_    = as_ + n;
    float* aself  = ad_ + n;                 // n
    int*   rowptr = (int*)(aself + n);       // n+1
    int*   ccnt   = rowptr + (n + 1);        // NB
    int*   cbase  = ccnt + NB;               // NB+1
    int*   ccur   = cbase + NB + 1;          // NB
    int*   colidx = ccur + NB;               // E
    float* alpha  = (float*)(colidx + E);    // E floats (6.4 MB)
    size_t wt_off = (((size_t)((char*)(alpha + E) - (char*)d_ws)) + 15) & ~(size_t)15;
    __half* Wt1h  = (__half*)((char*)d_ws + wt_off);          // 32 KB
    __half* Wt2h  = Wt1h + 128 * 128;                          // 32 KB

    // ---- weight transpose + CSR build (shared by both layers) ----
    k_wt<<<2, 1024, 0, stream>>>(W1, W2, Wt1h, Wt2h);
    hipMemsetAsync(ccnt, 0, (size_t)NB * sizeof(int), stream);
    k_chist<<<256, 256, 0, stream>>>(dst, ccnt, E, NB);
    k_cscan<<<1, 1024, 0, stream>>>(ccnt, cbase, ccur, NB, rowptr, n);
    const int SCAT_BLOCKS = 256;
    k_cscatter<<<SCAT_BLOCKS, 256, 0, stream>>>(src, dst, ccur, ebuf, E, NB, SCAT_BLOCKS);
    k_fine<<<NB, 256, 0, stream>>>(ebuf, cbase, rowptr, colidx, n);

    const int gemm_grid = (n + 63) / 64;
    const int node_grid = (n + 3) / 4;

    // ---- layer 1 ----
    k_gemm<<<gemm_grid, 256, 0, stream>>>(x, Wt1h, a1s, a1d, H, as_, ad_, n);
    k_alpha<<<node_grid, 256, 0, stream>>>(as_, ad_, rowptr, colidx, alpha, aself, n);
    k_aggr<<<node_grid, 256, 0, stream>>>(H, alpha, aself, rowptr, colidx, b1, dout, n, 1);

    // ---- layer 2 ----
    k_gemm<<<gemm_grid, 256, 0, stream>>>(dout, Wt2h, a2s, a2d, H, as_, ad_, n);
    k_alpha<<<node_grid, 256, 0, stream>>>(as_, ad_, rowptr, colidx, alpha, aself, n);
    k_aggr<<<node_grid, 256, 0, stream>>>(H, alpha, aself, rowptr, colidx, b2, dout, n, 0);
}

// Round 6
// 245.081 us; speedup vs baseline: 1.0872x; 1.0872x over previous
//
#include <hip/hip_runtime.h>
#include <hip/hip_bf16.h>
#include <hip/hip_fp16.h>

#define FD 128
#define CBW 64            // coarse bucket width: bucket = dst >> 6
#define NB_MAX 1024

typedef _Float16 half8 __attribute__((ext_vector_type(8)));
typedef float f32x4 __attribute__((ext_vector_type(4)));

// ---------------- coarse histogram (LDS-aggregated) ----------------
__global__ __launch_bounds__(256) void k_chist(const int* __restrict__ dst,
                                               int* __restrict__ ccnt, int e, int nb) {
    __shared__ int lh[NB_MAX];
    for (int i = threadIdx.x; i < nb; i += 256) lh[i] = 0;
    __syncthreads();
    for (int i = blockIdx.x * 256 + threadIdx.x; i < e; i += gridDim.x * 256)
        atomicAdd(&lh[dst[i] >> 6], 1);
    __syncthreads();
    for (int i = threadIdx.x; i < nb; i += 256) {
        int c = lh[i];
        if (c) atomicAdd(&ccnt[i], c);
    }
}

// ---------------- scan of coarse counts (single block) ----------------
__global__ void k_cscan(const int* __restrict__ ccnt, int* __restrict__ cbase,
                        int* __restrict__ ccur, int nb, int* __restrict__ rowptr, int n) {
    __shared__ int wsum[16];
    __shared__ int woff[17];
    const int t = threadIdx.x, lane = t & 63, wid = t >> 6;
    int carry = 0;
    for (int base = 0; base < nb; base += 1024) {
        int idx = base + t;
        int v = (idx < nb) ? ccnt[idx] : 0;
        int s = v;
#pragma unroll
        for (int off = 1; off < 64; off <<= 1) {
            int u = __shfl_up(s, off, 64);
            if (lane >= off) s += u;
        }
        if (lane == 63) wsum[wid] = s;
        __syncthreads();
        if (wid == 0) {
            int w2 = (lane < 16) ? wsum[lane] : 0;
#pragma unroll
            for (int off = 1; off < 16; off <<= 1) {
                int u = __shfl_up(w2, off, 64);
                if (lane >= off) w2 += u;
            }
            if (lane < 16) woff[lane + 1] = w2;
            if (lane == 0) woff[0] = 0;
        }
        __syncthreads();
        int excl = carry + woff[wid] + (s - v);
        if (idx < nb) { cbase[idx] = excl; ccur[idx] = excl; }
        carry += woff[16];
        __syncthreads();
    }
    if (t == 0) { cbase[nb] = carry; rowptr[n] = carry; }
}

// ---------------- coarse scatter: pack (src<<6 | dst&63) into bucket-major ebuf ----------------
__global__ __launch_bounds__(256) void k_cscatter(const int* __restrict__ src,
                                                  const int* __restrict__ dst,
                                                  int* __restrict__ ccur,
                                                  int* __restrict__ ebuf,
                                                  int e, int nb, int nblocks) {
    __shared__ int lh[NB_MAX];
    __shared__ int lb[NB_MAX];
    const int per = (e + nblocks - 1) / nblocks;
    const int lo = blockIdx.x * per;
    const int hi = min(e, lo + per);
    const int t = threadIdx.x;
    for (int i = t; i < nb; i += 256) lh[i] = 0;
    __syncthreads();
    for (int i = lo + t; i < hi; i += 256) atomicAdd(&lh[dst[i] >> 6], 1);
    __syncthreads();
    for (int i = t; i < nb; i += 256) {
        int c = lh[i];
        lb[i] = c ? atomicAdd(&ccur[i], c) : 0;
    }
    __syncthreads();
    for (int i = t; i < nb; i += 256) lh[i] = 0;
    __syncthreads();
    for (int i = lo + t; i < hi; i += 256) {
        int d = dst[i];
        int bkt = d >> 6;
        int r = atomicAdd(&lh[bkt], 1);
        ebuf[lb[bkt] + r] = (src[i] << 6) | (d & (CBW - 1));
    }
}

// ---------------- fine counting sort within each coarse bucket ----------------
__global__ __launch_bounds__(256) void k_fine(const int* __restrict__ ebuf,
                                              const int* __restrict__ cbase,
                                              int* __restrict__ rowptr,
                                              int* __restrict__ colidx, int n) {
    const int b = blockIdx.x;
    const int node0 = b * CBW;
    const int nloc = min(CBW, n - node0);
    const int beg = cbase[b], end = cbase[b + 1];
    __shared__ int fh[CBW];
    __shared__ int fo[CBW];
    const int t = threadIdx.x;
    if (t < CBW) fh[t] = 0;
    __syncthreads();
    for (int e = beg + t; e < end; e += 256) atomicAdd(&fh[ebuf[e] & (CBW - 1)], 1);
    __syncthreads();
    if (t < 64) {
        int v = fh[t];
        int s = v;
#pragma unroll
        for (int off = 1; off < 64; off <<= 1) {
            int u = __shfl_up(s, off, 64);
            if (t >= off) s += u;
        }
        fo[t] = s - v;
    }
    __syncthreads();
    if (t < nloc) rowptr[node0 + t] = beg + fo[t];
    if (t < CBW) fh[t] = 0;
    __syncthreads();
    for (int e = beg + t; e < end; e += 256) {
        int v = ebuf[e];
        int d = v & (CBW - 1);
        int r = atomicAdd(&fh[d], 1);
        colidx[beg + fo[d] + r] = v >> 6;
    }
}

// ---------------- W -> W^T fp16 ----------------
__global__ __launch_bounds__(1024) void k_wt(const float* __restrict__ Wa,
                                             const float* __restrict__ Wb,
                                             __half* __restrict__ Ta,
                                             __half* __restrict__ Tb) {
    __shared__ float sw[128 * 129];
    const float* W = blockIdx.x ? Wb : Wa;
    __half* T = blockIdx.x ? Tb : Ta;
    const int t = threadIdx.x;
#pragma unroll
    for (int i = 0; i < 16; i++) {
        int idx = i * 1024 + t;
        sw[(idx >> 7) * 129 + (idx & 127)] = W[idx];
    }
    __syncthreads();
#pragma unroll
    for (int i = 0; i < 8; i++) {
        int o = i * 1024 + t;
        int c = o >> 6, kp = o & 63;
        float lo = sw[(kp * 2) * 129 + c];
        float hi = sw[(kp * 2 + 1) * 129 + c];
        *(__half2*)&T[c * 128 + kp * 2] = __floats2half2_rn(lo, hi);
    }
}

// ---------------- x fp32 -> fp16 ----------------
__global__ __launch_bounds__(256) void k_x16(const float* __restrict__ x,
                                             __half* __restrict__ y, int count8) {
    int i = blockIdx.x * 256 + threadIdx.x;
    if (i >= count8) return;
    float4 a = *(const float4*)&x[(size_t)i * 8];
    float4 b = *(const float4*)&x[(size_t)i * 8 + 4];
    union { __half2 h2[4]; uint4 u; } pk;
    pk.h2[0] = __floats2half2_rn(a.x, a.y);
    pk.h2[1] = __floats2half2_rn(a.z, a.w);
    pk.h2[2] = __floats2half2_rn(b.x, b.y);
    pk.h2[3] = __floats2half2_rn(b.z, b.w);
    *(uint4*)&y[(size_t)i * 8] = pk.u;
}

// ---------------- MFMA GEMM: H = X @ W (fp16 in, fp32 acc) + fused dots ----------------
__global__ __launch_bounds__(256) void k_gemm(const __half* __restrict__ X,
                                              const __half* __restrict__ Wt,
                                              const float* __restrict__ a_s,
                                              const float* __restrict__ a_d,
                                              __half* __restrict__ H,
                                              float* __restrict__ as_,
                                              float* __restrict__ ad_, int n) {
    const int t = threadIdx.x;
    const int wave = t >> 6, lane = t & 63;
    const int g = lane >> 4, c16 = lane & 15;
    const int row0 = blockIdx.x * 64 + wave * 16;

    half8 A[4];
    {
        int row = row0 + c16;
        int rc = (row < n) ? row : (n - 1);
        const __half* xp = &X[(size_t)rc * 128 + g * 8];
#pragma unroll
        for (int kc = 0; kc < 4; kc++) A[kc] = *(const half8*)(xp + kc * 32);
    }

    f32x4 acc[8];
#pragma unroll
    for (int ct = 0; ct < 8; ct++) acc[ct] = (f32x4){0.f, 0.f, 0.f, 0.f};

#pragma unroll
    for (int ct = 0; ct < 8; ct++) {
        const __half* wp = &Wt[(ct * 16 + c16) * 128 + g * 8];
#pragma unroll
        for (int kc = 0; kc < 4; kc++) {
            half8 b = *(const half8*)(wp + kc * 32);
            acc[ct] = __builtin_amdgcn_mfma_f32_16x16x32_f16(A[kc], b, acc[ct], 0, 0, 0);
        }
    }

    float asv[8], adv[8];
#pragma unroll
    for (int ct = 0; ct < 8; ct++) {
        asv[ct] = a_s[ct * 16 + c16];
        adv[ct] = a_d[ct * 16 + c16];
    }
#pragma unroll
    for (int r = 0; r < 4; r++) {
        const int row = row0 + g * 4 + r;
        float vs = 0.f, vd = 0.f;
#pragma unroll
        for (int ct = 0; ct < 8; ct++) {
            float v = acc[ct][r];
            vs += v * asv[ct];
            vd += v * adv[ct];
            if (row < n) H[(size_t)row * 128 + ct * 16 + c16] = __float2half(v);
        }
#pragma unroll
        for (int off = 8; off; off >>= 1) {
            vs += __shfl_xor(vs, off, 16);
            vd += __shfl_xor(vd, off, 16);
        }
        if (c16 == 0 && row < n) { as_[row] = vs; ad_[row] = vd; }
    }
}

// ---------------- fused softmax + aggregation: wave/node, 4-deep pipeline ----------------
// Normalization applied at the end (softmax shift-invariance => skipping max-sub is exact;
// logits bounded, exp can't overflow fp32).
__device__ __forceinline__ void fmix8(float* acc, uint4 hv, float w) {
    union { uint4 u; _Float16 h[8]; } c;
    c.u = hv;
#pragma unroll
    for (int j = 0; j < 8; j++) acc[j] += w * (float)c.h[j];
}

__global__ __launch_bounds__(256) void k_aggr(const __half* __restrict__ H,
                                              const float* __restrict__ as_,
                                              const float* __restrict__ ad_,
                                              const int* __restrict__ rowptr,
                                              const int* __restrict__ colidx,
                                              const float* __restrict__ bias,
                                              float* __restrict__ outf,
                                              __half* __restrict__ outh,
                                              int n, int mode) {   // mode1: relu+fp16
    const int wid = threadIdx.x >> 6;
    const int lane = threadIdx.x & 63;
    const int node = blockIdx.x * 4 + wid;
    if (node >= n) return;
    const int q = lane >> 4;
    const int l = lane & 15;
    const int f0 = l * 8;
    const float adn = ad_[node];
    float s_acc = 0.f;
    float acc[8] = {0.f, 0.f, 0.f, 0.f, 0.f, 0.f, 0.f, 0.f};
    const int beg = rowptr[node], end = rowptr[node + 1];

    if (q == 3) {   // self loop (overlaps with pipeline startup)
        float e = as_[node] + adn;
        e = (e > 0.f) ? e : 0.2f * e;
        const float w = __expf(e);
        s_acc += w;
        fmix8(acc, *(const uint4*)&H[(size_t)node * 128 + f0], w);
    }

    int it = beg;
    int s[4]; float a[4];
#pragma unroll
    for (int j = 0; j < 4; j++) {
        int idx = it + q + 4 * j;
        s[j] = node; a[j] = -1e30f;
        if (idx < end) { s[j] = colidx[idx]; a[j] = as_[s[j]]; }
    }
    while (it < end) {
        uint4 h[4]; float w[4];
#pragma unroll
        for (int j = 0; j < 4; j++) {
            int idx = it + q + 4 * j;
            h[j] = make_uint4(0u, 0u, 0u, 0u);
            if (idx < end) h[j] = *(const uint4*)&H[(size_t)s[j] * 128 + f0];
        }
#pragma unroll
        for (int j = 0; j < 4; j++) {
            float e = a[j] + adn;
            e = (e > 0.f) ? e : 0.2f * e;
            w[j] = __expf(e);            // dead slot: exp(-inf) -> 0
        }
        const int nit = it + 16;
        int ns[4]; float na[4];
#pragma unroll
        for (int j = 0; j < 4; j++) {
            int idx = nit + q + 4 * j;
            ns[j] = node; na[j] = -1e30f;
            if (idx < end) { ns[j] = colidx[idx]; na[j] = as_[ns[j]]; }
        }
#pragma unroll
        for (int j = 0; j < 4; j++) { s_acc += w[j]; fmix8(acc, h[j], w[j]); }
#pragma unroll
        for (int j = 0; j < 4; j++) { s[j] = ns[j]; a[j] = na[j]; }
        it = nit;
    }

#pragma unroll
    for (int off = 16; off <= 32; off <<= 1) {
        s_acc += __shfl_xor(s_acc, off);
#pragma unroll
        for (int j = 0; j < 8; j++) acc[j] += __shfl_xor(acc[j], off);
    }
    if (q == 0) {
        const float inv = 1.f / s_acc;
        float o[8];
        const float4 b0 = *(const float4*)&bias[f0];
        const float4 b1 = *(const float4*)&bias[f0 + 4];
        o[0] = acc[0] * inv + b0.x; o[1] = acc[1] * inv + b0.y;
        o[2] = acc[2] * inv + b0.z; o[3] = acc[3] * inv + b0.w;
        o[4] = acc[4] * inv + b1.x; o[5] = acc[5] * inv + b1.y;
        o[6] = acc[6] * inv + b1.z; o[7] = acc[7] * inv + b1.w;
        if (mode == 1) {
#pragma unroll
            for (int j = 0; j < 8; j++) o[j] = fmaxf(o[j], 0.f);
            union { __half2 h2[4]; uint4 u; } pk;
            pk.h2[0] = __floats2half2_rn(o[0], o[1]);
            pk.h2[1] = __floats2half2_rn(o[2], o[3]);
            pk.h2[2] = __floats2half2_rn(o[4], o[5]);
            pk.h2[3] = __floats2half2_rn(o[6], o[7]);
            *(uint4*)&outh[(size_t)node * 128 + f0] = pk.u;
        } else {
            *(float4*)&outf[(size_t)node * 128 + f0] = make_float4(o[0], o[1], o[2], o[3]);
            *(float4*)&outf[(size_t)node * 128 + f0 + 4] = make_float4(o[4], o[5], o[6], o[7]);
        }
    }
}

extern "C" void kernel_launch(void* const* d_in, const int* in_sizes, int n_in,
                              void* d_out, int out_size, void* d_ws, size_t ws_size,
                              hipStream_t stream) {
    const float* x   = (const float*)d_in[0];
    const int*   ei  = (const int*)d_in[1];
    const float* W1  = (const float*)d_in[2];
    const float* a1s = (const float*)d_in[3];
    const float* a1d = (const float*)d_in[4];
    const float* b1  = (const float*)d_in[5];
    const float* W2  = (const float*)d_in[6];
    const float* a2s = (const float*)d_in[7];
    const float* a2d = (const float*)d_in[8];
    const float* b2  = (const float*)d_in[9];
    float* dout = (float*)d_out;

    const int n = in_sizes[0] / FD;          // 50000
    const int E = in_sizes[1] / 2;           // 1600000
    const int* src = ei;
    const int* dst = ei + E;
    const int NB = (n + CBW - 1) / CBW;      // 782 coarse buckets

    // workspace layout
    // buf0 (12.8 MB) is time-shared: ebuf (CSR build) -> x16 (gemm1 input) -> Y16 (layer1 out)
    char* base = (char*)d_ws;
    __half* buf0  = (__half*)base;                    // n*128 halves
    int*    ebuf  = (int*)base;                       // E ints (6.4 MB), aliases buf0
    __half* H     = (__half*)(base + (size_t)n * FD * sizeof(__half));
    float* as_    = (float*)((char*)H + (size_t)n * FD * sizeof(__half));
    float* ad_    = as_ + n;
    int*   rowptr = (int*)(ad_ + n);         // n+1
    int*   ccnt   = rowptr + (n + 1);        // NB
    int*   cbase  = ccnt + NB;               // NB+1
    int*   ccur   = cbase + NB + 1;          // NB
    int*   colidx = ccur + NB;               // E
    size_t wt_off = (((size_t)((char*)(colidx + E) - base)) + 15) & ~(size_t)15;
    __half* Wt1h  = (__half*)(base + wt_off);         // 32 KB
    __half* Wt2h  = Wt1h + 128 * 128;                  // 32 KB

    // ---- weight transpose + CSR build ----
    k_wt<<<2, 1024, 0, stream>>>(W1, W2, Wt1h, Wt2h);
    hipMemsetAsync(ccnt, 0, (size_t)NB * sizeof(int), stream);
    k_chist<<<256, 256, 0, stream>>>(dst, ccnt, E, NB);
    k_cscan<<<1, 1024, 0, stream>>>(ccnt, cbase, ccur, NB, rowptr, n);
    const int SCAT_BLOCKS = 256;
    k_cscatter<<<SCAT_BLOCKS, 256, 0, stream>>>(src, dst, ccur, ebuf, E, NB, SCAT_BLOCKS);
    k_fine<<<NB, 256, 0, stream>>>(ebuf, cbase, rowptr, colidx, n);

    // ---- x -> fp16 (buf0; ebuf is dead now) ----
    const int count8 = n * FD / 8;
    k_x16<<<(count8 + 255) / 256, 256, 0, stream>>>(x, buf0, count8);

    const int gemm_grid = (n + 63) / 64;
    const int node_grid = (n + 3) / 4;

    // ---- layer 1: gemm -> aggr (relu, fp16 out into buf0) ----
    k_gemm<<<gemm_grid, 256, 0, stream>>>(buf0, Wt1h, a1s, a1d, H, as_, ad_, n);
    k_aggr<<<node_grid, 256, 0, stream>>>(H, as_, ad_, rowptr, colidx, b1,
                                          nullptr, buf0, n, 1);

    // ---- layer 2: gemm -> aggr (fp32 out) ----
    k_gemm<<<gemm_grid, 256, 0, stream>>>(buf0, Wt2h, a2s, a2d, H, as_, ad_, n);
    k_aggr<<<node_grid, 256, 0, stream>>>(H, as_, ad_, rowptr, colidx, b2,
                                          dout, nullptr, n, 0);
}

// Round 7
// 237.883 us; speedup vs baseline: 1.1201x; 1.0303x over previous
//
#include <hip/hip_runtime.h>
#include <hip/hip_bf16.h>
#include <hip/hip_fp16.h>

#define FD 128
#define CBW 64            // coarse bucket width: bucket = dst >> 6
#define NB_MAX 1024

typedef _Float16 half8 __attribute__((ext_vector_type(8)));
typedef float f32x4 __attribute__((ext_vector_type(4)));

// ---------------- coarse histogram (LDS-aggregated) ----------------
__global__ __launch_bounds__(256) void k_chist(const int* __restrict__ dst,
                                               int* __restrict__ ccnt, int e, int nb) {
    __shared__ int lh[NB_MAX];
    for (int i = threadIdx.x; i < nb; i += 256) lh[i] = 0;
    __syncthreads();
    for (int i = blockIdx.x * 256 + threadIdx.x; i < e; i += gridDim.x * 256)
        atomicAdd(&lh[dst[i] >> 6], 1);
    __syncthreads();
    for (int i = threadIdx.x; i < nb; i += 256) {
        int c = lh[i];
        if (c) atomicAdd(&ccnt[i], c);
    }
}

// ---------------- scan of coarse counts (single block) ----------------
__global__ void k_cscan(const int* __restrict__ ccnt, int* __restrict__ cbase,
                        int* __restrict__ ccur, int nb, int* __restrict__ rowptr, int n) {
    __shared__ int wsum[16];
    __shared__ int woff[17];
    const int t = threadIdx.x, lane = t & 63, wid = t >> 6;
    int carry = 0;
    for (int base = 0; base < nb; base += 1024) {
        int idx = base + t;
        int v = (idx < nb) ? ccnt[idx] : 0;
        int s = v;
#pragma unroll
        for (int off = 1; off < 64; off <<= 1) {
            int u = __shfl_up(s, off, 64);
            if (lane >= off) s += u;
        }
        if (lane == 63) wsum[wid] = s;
        __syncthreads();
        if (wid == 0) {
            int w2 = (lane < 16) ? wsum[lane] : 0;
#pragma unroll
            for (int off = 1; off < 16; off <<= 1) {
                int u = __shfl_up(w2, off, 64);
                if (lane >= off) w2 += u;
            }
            if (lane < 16) woff[lane + 1] = w2;
            if (lane == 0) woff[0] = 0;
        }
        __syncthreads();
        int excl = carry + woff[wid] + (s - v);
        if (idx < nb) { cbase[idx] = excl; ccur[idx] = excl; }
        carry += woff[16];
        __syncthreads();
    }
    if (t == 0) { cbase[nb] = carry; rowptr[n] = carry; }
}

// ---------------- coarse scatter: pack (src<<6 | dst&63) into bucket-major ebuf ----------------
__global__ __launch_bounds__(256) void k_cscatter(const int* __restrict__ src,
                                                  const int* __restrict__ dst,
                                                  int* __restrict__ ccur,
                                                  int* __restrict__ ebuf,
                                                  int e, int nb, int nblocks) {
    __shared__ int lh[NB_MAX];
    __shared__ int lb[NB_MAX];
    const int per = (e + nblocks - 1) / nblocks;
    const int lo = blockIdx.x * per;
    const int hi = min(e, lo + per);
    const int t = threadIdx.x;
    for (int i = t; i < nb; i += 256) lh[i] = 0;
    __syncthreads();
    for (int i = lo + t; i < hi; i += 256) atomicAdd(&lh[dst[i] >> 6], 1);
    __syncthreads();
    for (int i = t; i < nb; i += 256) {
        int c = lh[i];
        lb[i] = c ? atomicAdd(&ccur[i], c) : 0;
    }
    __syncthreads();
    for (int i = t; i < nb; i += 256) lh[i] = 0;
    __syncthreads();
    for (int i = lo + t; i < hi; i += 256) {
        int d = dst[i];
        int bkt = d >> 6;
        int r = atomicAdd(&lh[bkt], 1);
        ebuf[lb[bkt] + r] = (src[i] << 6) | (d & (CBW - 1));
    }
}

// ---------------- fine counting sort within each coarse bucket ----------------
__global__ __launch_bounds__(256) void k_fine(const int* __restrict__ ebuf,
                                              const int* __restrict__ cbase,
                                              int* __restrict__ rowptr,
                                              int* __restrict__ colidx, int n) {
    const int b = blockIdx.x;
    const int node0 = b * CBW;
    const int nloc = min(CBW, n - node0);
    const int beg = cbase[b], end = cbase[b + 1];
    __shared__ int fh[CBW];
    __shared__ int fo[CBW];
    const int t = threadIdx.x;
    if (t < CBW) fh[t] = 0;
    __syncthreads();
    for (int e = beg + t; e < end; e += 256) atomicAdd(&fh[ebuf[e] & (CBW - 1)], 1);
    __syncthreads();
    if (t < 64) {
        int v = fh[t];
        int s = v;
#pragma unroll
        for (int off = 1; off < 64; off <<= 1) {
            int u = __shfl_up(s, off, 64);
            if (t >= off) s += u;
        }
        fo[t] = s - v;
    }
    __syncthreads();
    if (t < nloc) rowptr[node0 + t] = beg + fo[t];
    if (t < CBW) fh[t] = 0;
    __syncthreads();
    for (int e = beg + t; e < end; e += 256) {
        int v = ebuf[e];
        int d = v & (CBW - 1);
        int r = atomicAdd(&fh[d], 1);
        colidx[beg + fo[d] + r] = v >> 6;
    }
}

// ---------------- prep: W1,W2 -> W^T fp16 (blocks 0,1); x -> fp16 (blocks 2+) ----------------
__global__ __launch_bounds__(1024) void k_prep(const float* __restrict__ W1,
                                               const float* __restrict__ W2,
                                               __half* __restrict__ T1,
                                               __half* __restrict__ T2,
                                               const float* __restrict__ x,
                                               __half* __restrict__ x16, int count8) {
    const int t = threadIdx.x;
    if (blockIdx.x < 2) {
        __shared__ float sw[128 * 129];
        const float* W = blockIdx.x ? W2 : W1;
        __half* T = blockIdx.x ? T2 : T1;
#pragma unroll
        for (int i = 0; i < 16; i++) {
            int idx = i * 1024 + t;
            sw[(idx >> 7) * 129 + (idx & 127)] = W[idx];
        }
        __syncthreads();
#pragma unroll
        for (int i = 0; i < 8; i++) {
            int o = i * 1024 + t;
            int c = o >> 6, kp = o & 63;
            float lo = sw[(kp * 2) * 129 + c];
            float hi = sw[(kp * 2 + 1) * 129 + c];
            *(__half2*)&T[c * 128 + kp * 2] = __floats2half2_rn(lo, hi);
        }
    } else {
        int i = (blockIdx.x - 2) * 1024 + t;
        if (i >= count8) return;
        float4 a = *(const float4*)&x[(size_t)i * 8];
        float4 b = *(const float4*)&x[(size_t)i * 8 + 4];
        union { __half2 h2[4]; uint4 u; } pk;
        pk.h2[0] = __floats2half2_rn(a.x, a.y);
        pk.h2[1] = __floats2half2_rn(a.z, a.w);
        pk.h2[2] = __floats2half2_rn(b.x, b.y);
        pk.h2[3] = __floats2half2_rn(b.z, b.w);
        *(uint4*)&x16[(size_t)i * 8] = pk.u;
    }
}

// ---------------- MFMA GEMM: H = X @ W (fp16 in, fp32 acc) + fused dots ----------------
__global__ __launch_bounds__(256) void k_gemm(const __half* __restrict__ X,
                                              const __half* __restrict__ Wt,
                                              const float* __restrict__ a_s,
                                              const float* __restrict__ a_d,
                                              __half* __restrict__ H,
                                              float* __restrict__ as_,
                                              float* __restrict__ ad_, int n) {
    const int t = threadIdx.x;
    const int wave = t >> 6, lane = t & 63;
    const int g = lane >> 4, c16 = lane & 15;
    const int row0 = blockIdx.x * 64 + wave * 16;

    half8 A[4];
    {
        int row = row0 + c16;
        int rc = (row < n) ? row : (n - 1);
        const __half* xp = &X[(size_t)rc * 128 + g * 8];
#pragma unroll
        for (int kc = 0; kc < 4; kc++) A[kc] = *(const half8*)(xp + kc * 32);
    }

    f32x4 acc[8];
#pragma unroll
    for (int ct = 0; ct < 8; ct++) acc[ct] = (f32x4){0.f, 0.f, 0.f, 0.f};

#pragma unroll
    for (int ct = 0; ct < 8; ct++) {
        const __half* wp = &Wt[(ct * 16 + c16) * 128 + g * 8];
#pragma unroll
        for (int kc = 0; kc < 4; kc++) {
            half8 b = *(const half8*)(wp + kc * 32);
            acc[ct] = __builtin_amdgcn_mfma_f32_16x16x32_f16(A[kc], b, acc[ct], 0, 0, 0);
        }
    }

    float asv[8], adv[8];
#pragma unroll
    for (int ct = 0; ct < 8; ct++) {
        asv[ct] = a_s[ct * 16 + c16];
        adv[ct] = a_d[ct * 16 + c16];
    }
#pragma unroll
    for (int r = 0; r < 4; r++) {
        const int row = row0 + g * 4 + r;
        float vs = 0.f, vd = 0.f;
#pragma unroll
        for (int ct = 0; ct < 8; ct++) {
            float v = acc[ct][r];
            vs += v * asv[ct];
            vd += v * adv[ct];
            if (row < n) H[(size_t)row * 128 + ct * 16 + c16] = __float2half(v);
        }
#pragma unroll
        for (int off = 8; off; off >>= 1) {
            vs += __shfl_xor(vs, off, 16);
            vd += __shfl_xor(vd, off, 16);
        }
        if (c16 == 0 && row < n) { as_[row] = vs; ad_[row] = vd; }
    }
}

// ---------------- fused softmax + aggregation: wave/node, amortized scalar phase ----------------
// Superstep of 64 edges: phase A — each lane owns one edge (coalesced colidx,
// one exp per edge, w=0 for invalid); phase B — per 4-edge group, broadcast
// src/w via shuffle, 16-lane uint4 H-row load + fma_mix accumulate.
// End-normalization is exact (softmax shift-invariance; logits bounded).
__device__ __forceinline__ void fmix8(float* acc, uint4 hv, float w) {
    union { uint4 u; _Float16 h[8]; } c;
    c.u = hv;
#pragma unroll
    for (int j = 0; j < 8; j++) acc[j] += w * (float)c.h[j];
}

__global__ __launch_bounds__(256) void k_aggr(const __half* __restrict__ H,
                                              const float* __restrict__ as_,
                                              const float* __restrict__ ad_,
                                              const int* __restrict__ rowptr,
                                              const int* __restrict__ colidx,
                                              const float* __restrict__ bias,
                                              float* __restrict__ outf,
                                              __half* __restrict__ outh,
                                              int n, int mode) {   // mode1: relu+fp16 out
    const int wid = threadIdx.x >> 6;
    const int lane = threadIdx.x & 63;
    const int node = blockIdx.x * 4 + wid;
    if (node >= n) return;
    const int q = lane >> 4;
    const int boff = (lane & 15) * 16;      // byte offset of this lane's 8 halves
    const float adn = ad_[node];
    float sp = 0.f;                          // per-lane partial of sum(w)
    float acc[8] = {0.f, 0.f, 0.f, 0.f, 0.f, 0.f, 0.f, 0.f};
    const int beg = rowptr[node], end = rowptr[node + 1];

    {   // self loop
        float e = as_[node] + adn;
        e = (e > 0.f) ? e : 0.2f * e;
        const float w = __expf(e);
        if (lane == 63) sp += w;
        if (q == 3) {
            const uint4 hv = *(const uint4*)((const char*)H + (((unsigned)node << 8) + boff));
            fmix8(acc, hv, w);
        }
    }

    for (int it = beg; it < end; it += 64) {
        const int idx = it + lane;
        const bool valid = idx < end;
        const int idxc = valid ? idx : (end - 1);
        const int sl = colidx[idxc];
        float e = as_[sl] + adn;
        e = (e > 0.f) ? e : 0.2f * e;
        const float w = valid ? __expf(e) : 0.f;
        sp += w;
        int m = end - it; if (m > 64) m = 64;
        const int iters = (m + 3) >> 2;
        int slot = q;
#pragma unroll 4
        for (int g = 0; g < iters; ++g) {
            const int srcg = __shfl(sl, slot, 64);
            const float wg = __shfl(w, slot, 64);
            const uint4 hv = *(const uint4*)((const char*)H + (((unsigned)srcg << 8) + boff));
            fmix8(acc, hv, wg);
            slot += 4;
        }
    }

    // full-wave reduce of sum(w); quarter reduce of features
#pragma unroll
    for (int off = 1; off < 64; off <<= 1) sp += __shfl_xor(sp, off);
#pragma unroll
    for (int off = 16; off <= 32; off <<= 1) {
#pragma unroll
        for (int j = 0; j < 8; j++) acc[j] += __shfl_xor(acc[j], off);
    }
    if (q == 0) {
        const int f0 = boff >> 1;
        const float inv = 1.f / sp;
        float o[8];
        const float4 b0 = *(const float4*)&bias[f0];
        const float4 b1 = *(const float4*)&bias[f0 + 4];
        o[0] = acc[0] * inv + b0.x; o[1] = acc[1] * inv + b0.y;
        o[2] = acc[2] * inv + b0.z; o[3] = acc[3] * inv + b0.w;
        o[4] = acc[4] * inv + b1.x; o[5] = acc[5] * inv + b1.y;
        o[6] = acc[6] * inv + b1.z; o[7] = acc[7] * inv + b1.w;
        if (mode == 1) {
#pragma unroll
            for (int j = 0; j < 8; j++) o[j] = fmaxf(o[j], 0.f);
            union { __half2 h2[4]; uint4 u; } pk;
            pk.h2[0] = __floats2half2_rn(o[0], o[1]);
            pk.h2[1] = __floats2half2_rn(o[2], o[3]);
            pk.h2[2] = __floats2half2_rn(o[4], o[5]);
            pk.h2[3] = __floats2half2_rn(o[6], o[7]);
            *(uint4*)&outh[(size_t)node * 128 + f0] = pk.u;
        } else {
            *(float4*)&outf[(size_t)node * 128 + f0] = make_float4(o[0], o[1], o[2], o[3]);
            *(float4*)&outf[(size_t)node * 128 + f0 + 4] = make_float4(o[4], o[5], o[6], o[7]);
        }
    }
}

extern "C" void kernel_launch(void* const* d_in, const int* in_sizes, int n_in,
                              void* d_out, int out_size, void* d_ws, size_t ws_size,
                              hipStream_t stream) {
    const float* x   = (const float*)d_in[0];
    const int*   ei  = (const int*)d_in[1];
    const float* W1  = (const float*)d_in[2];
    const float* a1s = (const float*)d_in[3];
    const float* a1d = (const float*)d_in[4];
    const float* b1  = (const float*)d_in[5];
    const float* W2  = (const float*)d_in[6];
    const float* a2s = (const float*)d_in[7];
    const float* a2d = (const float*)d_in[8];
    const float* b2  = (const float*)d_in[9];
    float* dout = (float*)d_out;

    const int n = in_sizes[0] / FD;          // 50000
    const int E = in_sizes[1] / 2;           // 1600000
    const int* src = ei;
    const int* dst = ei + E;
    const int NB = (n + CBW - 1) / CBW;      // 782 coarse buckets

    // workspace layout
    // buf0 (12.8 MB) is time-shared: ebuf (CSR build) -> x16 (gemm1 input) -> Y16 (layer1 out)
    char* base = (char*)d_ws;
    __half* buf0  = (__half*)base;                    // n*128 halves
    int*    ebuf  = (int*)base;                       // E ints (6.4 MB), aliases buf0
    __half* H     = (__half*)(base + (size_t)n * FD * sizeof(__half));
    float* as_    = (float*)((char*)H + (size_t)n * FD * sizeof(__half));
    float* ad_    = as_ + n;
    int*   rowptr = (int*)(ad_ + n);         // n+1
    int*   ccnt   = rowptr + (n + 1);        // NB
    int*   cbase  = ccnt + NB;               // NB+1
    int*   ccur   = cbase + NB + 1;          // NB
    int*   colidx = ccur + NB;               // E
    size_t wt_off = (((size_t)((char*)(colidx + E) - base)) + 15) & ~(size_t)15;
    __half* Wt1h  = (__half*)(base + wt_off);         // 32 KB
    __half* Wt2h  = Wt1h + 128 * 128;                  // 32 KB

    // ---- CSR build ----
    hipMemsetAsync(ccnt, 0, (size_t)NB * sizeof(int), stream);
    k_chist<<<256, 256, 0, stream>>>(dst, ccnt, E, NB);
    k_cscan<<<1, 1024, 0, stream>>>(ccnt, cbase, ccur, NB, rowptr, n);
    const int SCAT_BLOCKS = 256;
    k_cscatter<<<SCAT_BLOCKS, 256, 0, stream>>>(src, dst, ccur, ebuf, E, NB, SCAT_BLOCKS);
    k_fine<<<NB, 256, 0, stream>>>(ebuf, cbase, rowptr, colidx, n);

    // ---- weights transpose + x -> fp16 (buf0; ebuf dead now) ----
    const int count8 = n * FD / 8;
    const int prep_grid = 2 + (count8 + 1023) / 1024;
    k_prep<<<prep_grid, 1024, 0, stream>>>(W1, W2, Wt1h, Wt2h, x, buf0, count8);

    const int gemm_grid = (n + 63) / 64;
    const int node_grid = (n + 3) / 4;

    // ---- layer 1: gemm -> aggr (relu, fp16 out into buf0) ----
    k_gemm<<<gemm_grid, 256, 0, stream>>>(buf0, Wt1h, a1s, a1d, H, as_, ad_, n);
    k_aggr<<<node_grid, 256, 0, stream>>>(H, as_, ad_, rowptr, colidx, b1,
                                          nullptr, buf0, n, 1);

    // ---- layer 2: gemm -> aggr (fp32 out) ----
    k_gemm<<<gemm_grid, 256, 0, stream>>>(buf0, Wt2h, a2s, a2d, H, as_, ad_, n);
    k_aggr<<<node_grid, 256, 0, stream>>>(H, as_, ad_, rowptr, colidx, b2,
                                          dout, nullptr, n, 0);
}

// Round 8
// 226.758 us; speedup vs baseline: 1.1751x; 1.0491x over previous
//
#include <hip/hip_runtime.h>
#include <hip/hip_bf16.h>
#include <hip/hip_fp16.h>

#define FD 128
#define CBW 256           // coarse bucket width: bucket = dst >> 8
#define NBK 256           // max buckets

typedef _Float16 half8 __attribute__((ext_vector_type(8)));
typedef float f32x4 __attribute__((ext_vector_type(4)));

// ---------------- fused: coarse histogram (blocks 0..255) + W->W^T fp16 (blocks 256,257) ----------------
__global__ __launch_bounds__(256) void k_pre(const int* __restrict__ dst,
                                             int* __restrict__ ccnt, int e, int nb,
                                             const float* __restrict__ W1,
                                             const float* __restrict__ W2,
                                             __half* __restrict__ T1,
                                             __half* __restrict__ T2) {
    __shared__ float sw[128 * 129];
    const int t = threadIdx.x;
    if (blockIdx.x < 256) {
        int* lh = (int*)sw;
        if (t < NBK) lh[t] = 0;
        __syncthreads();
        for (int i = blockIdx.x * 256 + t; i < e; i += 256 * 256)
            atomicAdd(&lh[dst[i] >> 8], 1);
        __syncthreads();
        if (t < nb) {
            int c = lh[t];
            if (c) atomicAdd(&ccnt[t], c);
        }
    } else {
        const float* W = (blockIdx.x == 257) ? W2 : W1;
        __half* T = (blockIdx.x == 257) ? T2 : T1;
#pragma unroll
        for (int i = 0; i < 64; i++) {
            int idx = i * 256 + t;
            sw[(idx >> 7) * 129 + (idx & 127)] = W[idx];
        }
        __syncthreads();
#pragma unroll
        for (int i = 0; i < 32; i++) {
            int o = i * 256 + t;
            int c = o >> 6, kp = o & 63;
            float lo = sw[(kp * 2) * 129 + c];
            float hi = sw[(kp * 2 + 1) * 129 + c];
            *(__half2*)&T[c * 128 + kp * 2] = __floats2half2_rn(lo, hi);
        }
    }
}

// ---------------- scan of coarse counts (single block, nb<=1024) ----------------
__global__ void k_cscan(const int* __restrict__ ccnt, int* __restrict__ cbase,
                        int* __restrict__ ccur, int nb, int* __restrict__ rowptr, int n) {
    __shared__ int wsum[16];
    __shared__ int woff[17];
    const int t = threadIdx.x, lane = t & 63, wid = t >> 6;
    int v = (t < nb) ? ccnt[t] : 0;
    int s = v;
#pragma unroll
    for (int off = 1; off < 64; off <<= 1) {
        int u = __shfl_up(s, off, 64);
        if (lane >= off) s += u;
    }
    if (lane == 63) wsum[wid] = s;
    __syncthreads();
    if (wid == 0) {
        int w2 = (lane < 16) ? wsum[lane] : 0;
#pragma unroll
        for (int off = 1; off < 16; off <<= 1) {
            int u = __shfl_up(w2, off, 64);
            if (lane >= off) w2 += u;
        }
        if (lane < 16) woff[lane + 1] = w2;
        if (lane == 0) woff[0] = 0;
    }
    __syncthreads();
    int excl = woff[wid] + (s - v);
    if (t < nb) { cbase[t] = excl; ccur[t] = excl; }
    if (t == 0) { cbase[nb] = woff[16]; rowptr[n] = woff[16]; }
}

// ---------------- fused: coarse scatter (blocks 0..nscat-1) + layer1 GEMM (rest) ----------------
__global__ __launch_bounds__(256) void k_mid(const int* __restrict__ src,
                                             const int* __restrict__ dst,
                                             int* __restrict__ ccur,
                                             int* __restrict__ ebuf,
                                             int e, int nb, int nscat,
                                             const float* __restrict__ X,
                                             const __half* __restrict__ Wt,
                                             const float* __restrict__ a_s,
                                             const float* __restrict__ a_d,
                                             __half* __restrict__ H,
                                             float* __restrict__ as_,
                                             float* __restrict__ ad_, int n) {
    __shared__ int lh[NBK];
    __shared__ int lb[NBK];
    const int t = threadIdx.x;
    if ((int)blockIdx.x < nscat) {
        const int per = (e + nscat - 1) / nscat;
        const int lo = blockIdx.x * per;
        const int hi = min(e, lo + per);
        if (t < NBK) lh[t] = 0;
        __syncthreads();
        for (int i = lo + t; i < hi; i += 256) atomicAdd(&lh[dst[i] >> 8], 1);
        __syncthreads();
        if (t < nb) {
            int c = lh[t];
            lb[t] = c ? atomicAdd(&ccur[t], c) : 0;
        }
        __syncthreads();
        if (t < NBK) lh[t] = 0;
        __syncthreads();
        for (int i = lo + t; i < hi; i += 256) {
            int d = dst[i];
            int bkt = d >> 8;
            int r = atomicAdd(&lh[bkt], 1);
            ebuf[lb[bkt] + r] = (src[i] << 8) | (d & (CBW - 1));
        }
    } else {
        const int bid = blockIdx.x - nscat;
        const int wave = t >> 6, lane = t & 63;
        const int g = lane >> 4, c16 = lane & 15;
        const int row0 = bid * 64 + wave * 16;

        half8 A[4];
        {
            int row = row0 + c16;
            int rc = (row < n) ? row : (n - 1);
            const float* xp = &X[(size_t)rc * 128 + g * 8];
#pragma unroll
            for (int kc = 0; kc < 4; kc++) {
                float4 x0 = *(const float4*)(xp + kc * 32);
                float4 x1 = *(const float4*)(xp + kc * 32 + 4);
                half8 a;
                a[0] = (_Float16)x0.x; a[1] = (_Float16)x0.y;
                a[2] = (_Float16)x0.z; a[3] = (_Float16)x0.w;
                a[4] = (_Float16)x1.x; a[5] = (_Float16)x1.y;
                a[6] = (_Float16)x1.z; a[7] = (_Float16)x1.w;
                A[kc] = a;
            }
        }
        f32x4 acc[8];
#pragma unroll
        for (int ct = 0; ct < 8; ct++) acc[ct] = (f32x4){0.f, 0.f, 0.f, 0.f};
#pragma unroll
        for (int ct = 0; ct < 8; ct++) {
            const __half* wp = &Wt[(ct * 16 + c16) * 128 + g * 8];
#pragma unroll
            for (int kc = 0; kc < 4; kc++) {
                half8 b = *(const half8*)(wp + kc * 32);
                acc[ct] = __builtin_amdgcn_mfma_f32_16x16x32_f16(A[kc], b, acc[ct], 0, 0, 0);
            }
        }
        float asv[8], adv[8];
#pragma unroll
        for (int ct = 0; ct < 8; ct++) {
            asv[ct] = a_s[ct * 16 + c16];
            adv[ct] = a_d[ct * 16 + c16];
        }
#pragma unroll
        for (int r = 0; r < 4; r++) {
            const int row = row0 + g * 4 + r;
            float vs = 0.f, vd = 0.f;
#pragma unroll
            for (int ct = 0; ct < 8; ct++) {
                float v = acc[ct][r];
                vs += v * asv[ct];
                vd += v * adv[ct];
                if (row < n) H[(size_t)row * 128 + ct * 16 + c16] = __float2half(v);
            }
#pragma unroll
            for (int off = 8; off; off >>= 1) {
                vs += __shfl_xor(vs, off, 16);
                vd += __shfl_xor(vd, off, 16);
            }
            if (c16 == 0 && row < n) { as_[row] = vs; ad_[row] = vd; }
        }
    }
}

// ---------------- fine counting sort within each coarse bucket (CBW=256) ----------------
__global__ __launch_bounds__(256) void k_fine(const int* __restrict__ ebuf,
                                              const int* __restrict__ cbase,
                                              int* __restrict__ rowptr,
                                              int* __restrict__ colidx, int n) {
    const int b = blockIdx.x;
    const int node0 = b * CBW;
    const int nloc = min(CBW, n - node0);
    const int beg = cbase[b], end = cbase[b + 1];
    __shared__ int fh[CBW];
    __shared__ int fo[CBW];
    __shared__ int wt4[4];
    const int t = threadIdx.x, lane = t & 63, wid = t >> 6;
    fh[t] = 0;
    __syncthreads();
    for (int e = beg + t; e < end; e += 256) atomicAdd(&fh[ebuf[e] & (CBW - 1)], 1);
    __syncthreads();
    {
        int v = fh[t];
        int s = v;
#pragma unroll
        for (int off = 1; off < 64; off <<= 1) {
            int u = __shfl_up(s, off, 64);
            if (lane >= off) s += u;
        }
        if (lane == 63) wt4[wid] = s;
        __syncthreads();
        int wo = 0;
#pragma unroll
        for (int j = 0; j < 4; j++) wo += (j < wid) ? wt4[j] : 0;
        fo[t] = wo + s - v;
    }
    __syncthreads();
    if (t < nloc) rowptr[node0 + t] = beg + fo[t];
    fh[t] = 0;
    __syncthreads();
    for (int e = beg + t; e < end; e += 256) {
        int v = ebuf[e];
        int d = v & (CBW - 1);
        int r = atomicAdd(&fh[d], 1);
        colidx[beg + fo[d] + r] = v >> 8;
    }
}

// ---------------- MFMA GEMM (fp16 input) + fused dots ----------------
__global__ __launch_bounds__(256) void k_gemm(const __half* __restrict__ X,
                                              const __half* __restrict__ Wt,
                                              const float* __restrict__ a_s,
                                              const float* __restrict__ a_d,
                                              __half* __restrict__ H,
                                              float* __restrict__ as_,
                                              float* __restrict__ ad_, int n) {
    const int t = threadIdx.x;
    const int wave = t >> 6, lane = t & 63;
    const int g = lane >> 4, c16 = lane & 15;
    const int row0 = blockIdx.x * 64 + wave * 16;

    half8 A[4];
    {
        int row = row0 + c16;
        int rc = (row < n) ? row : (n - 1);
        const __half* xp = &X[(size_t)rc * 128 + g * 8];
#pragma unroll
        for (int kc = 0; kc < 4; kc++) A[kc] = *(const half8*)(xp + kc * 32);
    }
    f32x4 acc[8];
#pragma unroll
    for (int ct = 0; ct < 8; ct++) acc[ct] = (f32x4){0.f, 0.f, 0.f, 0.f};
#pragma unroll
    for (int ct = 0; ct < 8; ct++) {
        const __half* wp = &Wt[(ct * 16 + c16) * 128 + g * 8];
#pragma unroll
        for (int kc = 0; kc < 4; kc++) {
            half8 b = *(const half8*)(wp + kc * 32);
            acc[ct] = __builtin_amdgcn_mfma_f32_16x16x32_f16(A[kc], b, acc[ct], 0, 0, 0);
        }
    }
    float asv[8], adv[8];
#pragma unroll
    for (int ct = 0; ct < 8; ct++) {
        asv[ct] = a_s[ct * 16 + c16];
        adv[ct] = a_d[ct * 16 + c16];
    }
#pragma unroll
    for (int r = 0; r < 4; r++) {
        const int row = row0 + g * 4 + r;
        float vs = 0.f, vd = 0.f;
#pragma unroll
        for (int ct = 0; ct < 8; ct++) {
            float v = acc[ct][r];
            vs += v * asv[ct];
            vd += v * adv[ct];
            if (row < n) H[(size_t)row * 128 + ct * 16 + c16] = __float2half(v);
        }
#pragma unroll
        for (int off = 8; off; off >>= 1) {
            vs += __shfl_xor(vs, off, 16);
            vd += __shfl_xor(vd, off, 16);
        }
        if (c16 == 0 && row < n) { as_[row] = vs; ad_[row] = vd; }
    }
}

// ---------------- fused softmax + aggregation ----------------
__device__ __forceinline__ void fmix8(float* acc, uint4 hv, float w) {
    union { uint4 u; _Float16 h[8]; } c;
    c.u = hv;
#pragma unroll
    for (int j = 0; j < 8; j++) acc[j] += w * (float)c.h[j];
}

__global__ __launch_bounds__(256) void k_aggr(const __half* __restrict__ H,
                                              const float* __restrict__ as_,
                                              const float* __restrict__ ad_,
                                              const int* __restrict__ rowptr,
                                              const int* __restrict__ colidx,
                                              const float* __restrict__ bias,
                                              float* __restrict__ outf,
                                              __half* __restrict__ outh,
                                              int n, int mode) {   // mode1: relu+fp16 out
    const int wid = threadIdx.x >> 6;
    const int lane = threadIdx.x & 63;
    const int node = blockIdx.x * 4 + wid;
    if (node >= n) return;
    const int q = lane >> 4;
    const int boff = (lane & 15) * 16;
    const float adn = ad_[node];
    float sp = 0.f;
    float acc[8] = {0.f, 0.f, 0.f, 0.f, 0.f, 0.f, 0.f, 0.f};
    const int beg = rowptr[node], end = rowptr[node + 1];

    {   // self loop
        float e = as_[node] + adn;
        e = (e > 0.f) ? e : 0.2f * e;
        const float w = __expf(e);
        if (lane == 63) sp += w;
        if (q == 3) {
            const uint4 hv = *(const uint4*)((const char*)H + (((unsigned)node << 8) + boff));
            fmix8(acc, hv, w);
        }
    }

    for (int it = beg; it < end; it += 64) {
        const int idx = it + lane;
        const bool valid = idx < end;
        const int idxc = valid ? idx : (end - 1);
        const int sl = colidx[idxc];
        float e = as_[sl] + adn;
        e = (e > 0.f) ? e : 0.2f * e;
        const float w = valid ? __expf(e) : 0.f;
        sp += w;
        // pack (src, w_fp16) into one shuffle word
        const int pk = (sl << 16) | (int)__half_as_ushort(__float2half(w));
        int m = end - it; if (m > 64) m = 64;
        const int iters = (m + 3) >> 2;
        int slot = q;
#pragma unroll 4
        for (int g = 0; g < iters; ++g) {
            const int pg = __shfl(pk, slot, 64);
            const unsigned srcg = ((unsigned)pg) >> 16;
            const float wg = __half2float(__ushort_as_half((unsigned short)(pg & 0xffff)));
            const uint4 hv = *(const uint4*)((const char*)H + ((srcg << 8) + boff));
            fmix8(acc, hv, wg);
            slot += 4;
        }
    }

#pragma unroll
    for (int off = 1; off < 64; off <<= 1) sp += __shfl_xor(sp, off);
#pragma unroll
    for (int off = 16; off <= 32; off <<= 1) {
#pragma unroll
        for (int j = 0; j < 8; j++) acc[j] += __shfl_xor(acc[j], off);
    }
    if (q == 0) {
        const int f0 = boff >> 1;
        const float inv = 1.f / sp;
        float o[8];
        const float4 b0 = *(const float4*)&bias[f0];
        const float4 b1 = *(const float4*)&bias[f0 + 4];
        o[0] = acc[0] * inv + b0.x; o[1] = acc[1] * inv + b0.y;
        o[2] = acc[2] * inv + b0.z; o[3] = acc[3] * inv + b0.w;
        o[4] = acc[4] * inv + b1.x; o[5] = acc[5] * inv + b1.y;
        o[6] = acc[6] * inv + b1.z; o[7] = acc[7] * inv + b1.w;
        if (mode == 1) {
#pragma unroll
            for (int j = 0; j < 8; j++) o[j] = fmaxf(o[j], 0.f);
            union { __half2 h2[4]; uint4 u; } pkk;
            pkk.h2[0] = __floats2half2_rn(o[0], o[1]);
            pkk.h2[1] = __floats2half2_rn(o[2], o[3]);
            pkk.h2[2] = __floats2half2_rn(o[4], o[5]);
            pkk.h2[3] = __floats2half2_rn(o[6], o[7]);
            *(uint4*)&outh[(size_t)node * 128 + f0] = pkk.u;
        } else {
            *(float4*)&outf[(size_t)node * 128 + f0] = make_float4(o[0], o[1], o[2], o[3]);
            *(float4*)&outf[(size_t)node * 128 + f0 + 4] = make_float4(o[4], o[5], o[6], o[7]);
        }
    }
}

extern "C" void kernel_launch(void* const* d_in, const int* in_sizes, int n_in,
                              void* d_out, int out_size, void* d_ws, size_t ws_size,
                              hipStream_t stream) {
    const float* x   = (const float*)d_in[0];
    const int*   ei  = (const int*)d_in[1];
    const float* W1  = (const float*)d_in[2];
    const float* a1s = (const float*)d_in[3];
    const float* a1d = (const float*)d_in[4];
    const float* b1  = (const float*)d_in[5];
    const float* W2  = (const float*)d_in[6];
    const float* a2s = (const float*)d_in[7];
    const float* a2d = (const float*)d_in[8];
    const float* b2  = (const float*)d_in[9];
    float* dout = (float*)d_out;

    const int n = in_sizes[0] / FD;          // 50000
    const int E = in_sizes[1] / 2;           // 1600000
    const int* src = ei;
    const int* dst = ei + E;
    const int NB = (n + CBW - 1) / CBW;      // 196 coarse buckets

    // workspace layout
    // buf0 (12.8 MB) time-shared: ebuf (CSR build) -> Y16 (layer1 output)
    char* base = (char*)d_ws;
    __half* buf0  = (__half*)base;                    // n*128 halves
    int*    ebuf  = (int*)base;                       // E ints (6.4 MB), aliases buf0
    __half* H     = (__half*)(base + (size_t)n * FD * sizeof(__half));
    float* as_    = (float*)((char*)H + (size_t)n * FD * sizeof(__half));
    float* ad_    = as_ + n;
    int*   rowptr = (int*)(ad_ + n);         // n+1
    int*   ccnt   = rowptr + (n + 1);        // NB
    int*   cbase  = ccnt + NB;               // NB+1
    int*   ccur   = cbase + NB + 1;          // NB
    int*   colidx = ccur + NB;               // E
    size_t wt_off = (((size_t)((char*)(colidx + E) - base)) + 15) & ~(size_t)15;
    __half* Wt1h  = (__half*)(base + wt_off);         // 32 KB
    __half* Wt2h  = Wt1h + 128 * 128;                  // 32 KB

    const int gemm_grid = (n + 63) / 64;     // 782
    const int node_grid = (n + 3) / 4;       // 12500
    const int SCAT = 256;

    // ---- D0: zero coarse counts ----
    hipMemsetAsync(ccnt, 0, (size_t)NB * sizeof(int), stream);
    // ---- D1: coarse hist || weight transpose ----
    k_pre<<<258, 256, 0, stream>>>(dst, ccnt, E, NB, W1, W2, Wt1h, Wt2h);
    // ---- D2: scan ----
    k_cscan<<<1, 1024, 0, stream>>>(ccnt, cbase, ccur, NB, rowptr, n);
    // ---- D3: coarse scatter || layer-1 GEMM (reads fp32 x) ----
    k_mid<<<SCAT + gemm_grid, 256, 0, stream>>>(src, dst, ccur, ebuf, E, NB, SCAT,
                                                x, Wt1h, a1s, a1d, H, as_, ad_, n);
    // ---- D4: fine sort -> colidx/rowptr ----
    k_fine<<<NB, 256, 0, stream>>>(ebuf, cbase, rowptr, colidx, n);
    // ---- D5: layer-1 aggregate (relu, fp16 out into buf0; ebuf dead) ----
    k_aggr<<<node_grid, 256, 0, stream>>>(H, as_, ad_, rowptr, colidx, b1,
                                          nullptr, buf0, n, 1);
    // ---- D6: layer-2 GEMM (fp16 input) ----
    k_gemm<<<gemm_grid, 256, 0, stream>>>(buf0, Wt2h, a2s, a2d, H, as_, ad_, n);
    // ---- D7: layer-2 aggregate (fp32 out) ----
    k_aggr<<<node_grid, 256, 0, stream>>>(H, as_, ad_, rowptr, colidx, b2,
                                          dout, nullptr, n, 0);
}

// Round 9
// 219.239 us; speedup vs baseline: 1.2154x; 1.0343x over previous
//
#include <hip/hip_runtime.h>
#include <hip/hip_bf16.h>
#include <hip/hip_fp16.h>

#define FD 128
#define CBW 256           // coarse bucket width: bucket = dst >> 8
#define NBK 256           // max buckets

typedef _Float16 half8 __attribute__((ext_vector_type(8)));
typedef float f32x4 __attribute__((ext_vector_type(4)));

// ---------------- fused: coarse histogram (blocks 0..255) + W->W^T fp16 (blocks 256,257) ----------------
__global__ __launch_bounds__(256) void k_pre(const int* __restrict__ dst,
                                             int* __restrict__ ccnt, int e, int nb,
                                             const float* __restrict__ W1,
                                             const float* __restrict__ W2,
                                             __half* __restrict__ T1,
                                             __half* __restrict__ T2) {
    __shared__ float sw[128 * 129];
    const int t = threadIdx.x;
    if (blockIdx.x < 256) {
        int* lh = (int*)sw;
        if (t < NBK) lh[t] = 0;
        __syncthreads();
        for (int i = blockIdx.x * 256 + t; i < e; i += 256 * 256)
            atomicAdd(&lh[dst[i] >> 8], 1);
        __syncthreads();
        if (t < nb) {
            int c = lh[t];
            if (c) atomicAdd(&ccnt[t], c);
        }
    } else {
        const float* W = (blockIdx.x == 257) ? W2 : W1;
        __half* T = (blockIdx.x == 257) ? T2 : T1;
#pragma unroll
        for (int i = 0; i < 64; i++) {
            int idx = i * 256 + t;
            sw[(idx >> 7) * 129 + (idx & 127)] = W[idx];
        }
        __syncthreads();
#pragma unroll
        for (int i = 0; i < 32; i++) {
            int o = i * 256 + t;
            int c = o >> 6, kp = o & 63;
            float lo = sw[(kp * 2) * 129 + c];
            float hi = sw[(kp * 2 + 1) * 129 + c];
            *(__half2*)&T[c * 128 + kp * 2] = __floats2half2_rn(lo, hi);
        }
    }
}

// ---------------- scan of coarse counts (single block, nb<=1024) ----------------
__global__ void k_cscan(const int* __restrict__ ccnt, int* __restrict__ cbase,
                        int* __restrict__ ccur, int nb, int* __restrict__ rowptr, int n) {
    __shared__ int wsum[16];
    __shared__ int woff[17];
    const int t = threadIdx.x, lane = t & 63, wid = t >> 6;
    int v = (t < nb) ? ccnt[t] : 0;
    int s = v;
#pragma unroll
    for (int off = 1; off < 64; off <<= 1) {
        int u = __shfl_up(s, off, 64);
        if (lane >= off) s += u;
    }
    if (lane == 63) wsum[wid] = s;
    __syncthreads();
    if (wid == 0) {
        int w2 = (lane < 16) ? wsum[lane] : 0;
#pragma unroll
        for (int off = 1; off < 16; off <<= 1) {
            int u = __shfl_up(w2, off, 64);
            if (lane >= off) w2 += u;
        }
        if (lane < 16) woff[lane + 1] = w2;
        if (lane == 0) woff[0] = 0;
    }
    __syncthreads();
    int excl = woff[wid] + (s - v);
    if (t < nb) { cbase[t] = excl; ccur[t] = excl; }
    if (t == 0) { cbase[nb] = woff[16]; rowptr[n] = woff[16]; }
}

// ---------------- fused: coarse scatter (blocks 0..nscat-1) + layer1 GEMM (rest) ----------------
__global__ __launch_bounds__(256) void k_mid(const int* __restrict__ src,
                                             const int* __restrict__ dst,
                                             int* __restrict__ ccur,
                                             int* __restrict__ ebuf,
                                             int e, int nb, int nscat,
                                             const float* __restrict__ X,
                                             const __half* __restrict__ Wt,
                                             const float* __restrict__ a_s,
                                             const float* __restrict__ a_d,
                                             __half* __restrict__ H,
                                             float* __restrict__ as_,
                                             float* __restrict__ ad_, int n) {
    __shared__ int lh[NBK];
    __shared__ int lb[NBK];
    const int t = threadIdx.x;
    if ((int)blockIdx.x < nscat) {
        const int per = (e + nscat - 1) / nscat;
        const int lo = blockIdx.x * per;
        const int hi = min(e, lo + per);
        if (t < NBK) lh[t] = 0;
        __syncthreads();
        for (int i = lo + t; i < hi; i += 256) atomicAdd(&lh[dst[i] >> 8], 1);
        __syncthreads();
        if (t < nb) {
            int c = lh[t];
            lb[t] = c ? atomicAdd(&ccur[t], c) : 0;
        }
        __syncthreads();
        if (t < NBK) lh[t] = 0;
        __syncthreads();
        for (int i = lo + t; i < hi; i += 256) {
            int d = dst[i];
            int bkt = d >> 8;
            int r = atomicAdd(&lh[bkt], 1);
            ebuf[lb[bkt] + r] = (src[i] << 8) | (d & (CBW - 1));
        }
    } else {
        const int bid = blockIdx.x - nscat;
        const int wave = t >> 6, lane = t & 63;
        const int g = lane >> 4, c16 = lane & 15;
        const int row0 = bid * 64 + wave * 16;

        half8 A[4];
        {
            int row = row0 + c16;
            int rc = (row < n) ? row : (n - 1);
            const float* xp = &X[(size_t)rc * 128 + g * 8];
#pragma unroll
            for (int kc = 0; kc < 4; kc++) {
                float4 x0 = *(const float4*)(xp + kc * 32);
                float4 x1 = *(const float4*)(xp + kc * 32 + 4);
                half8 a;
                a[0] = (_Float16)x0.x; a[1] = (_Float16)x0.y;
                a[2] = (_Float16)x0.z; a[3] = (_Float16)x0.w;
                a[4] = (_Float16)x1.x; a[5] = (_Float16)x1.y;
                a[6] = (_Float16)x1.z; a[7] = (_Float16)x1.w;
                A[kc] = a;
            }
        }
        f32x4 acc[8];
#pragma unroll
        for (int ct = 0; ct < 8; ct++) acc[ct] = (f32x4){0.f, 0.f, 0.f, 0.f};
#pragma unroll
        for (int ct = 0; ct < 8; ct++) {
            const __half* wp = &Wt[(ct * 16 + c16) * 128 + g * 8];
#pragma unroll
            for (int kc = 0; kc < 4; kc++) {
                half8 b = *(const half8*)(wp + kc * 32);
                acc[ct] = __builtin_amdgcn_mfma_f32_16x16x32_f16(A[kc], b, acc[ct], 0, 0, 0);
            }
        }
        float asv[8], adv[8];
#pragma unroll
        for (int ct = 0; ct < 8; ct++) {
            asv[ct] = a_s[ct * 16 + c16];
            adv[ct] = a_d[ct * 16 + c16];
        }
#pragma unroll
        for (int r = 0; r < 4; r++) {
            const int row = row0 + g * 4 + r;
            float vs = 0.f, vd = 0.f;
#pragma unroll
            for (int ct = 0; ct < 8; ct++) {
                float v = acc[ct][r];
                vs += v * asv[ct];
                vd += v * adv[ct];
                if (row < n) H[(size_t)row * 128 + ct * 16 + c16] = __float2half(v);
            }
#pragma unroll
            for (int off = 8; off; off >>= 1) {
                vs += __shfl_xor(vs, off, 16);
                vd += __shfl_xor(vd, off, 16);
            }
            if (c16 == 0 && row < n) { as_[row] = vs; ad_[row] = vd; }
        }
    }
}

// ---------------- fine counting sort within each coarse bucket (CBW=256) ----------------
__global__ __launch_bounds__(256) void k_fine(const int* __restrict__ ebuf,
                                              const int* __restrict__ cbase,
                                              int* __restrict__ rowptr,
                                              int* __restrict__ colidx, int n) {
    const int b = blockIdx.x;
    const int node0 = b * CBW;
    const int nloc = min(CBW, n - node0);
    const int beg = cbase[b], end = cbase[b + 1];
    __shared__ int fh[CBW];
    __shared__ int fo[CBW];
    __shared__ int wt4[4];
    const int t = threadIdx.x, lane = t & 63, wid = t >> 6;
    fh[t] = 0;
    __syncthreads();
    for (int e = beg + t; e < end; e += 256) atomicAdd(&fh[ebuf[e] & (CBW - 1)], 1);
    __syncthreads();
    {
        int v = fh[t];
        int s = v;
#pragma unroll
        for (int off = 1; off < 64; off <<= 1) {
            int u = __shfl_up(s, off, 64);
            if (lane >= off) s += u;
        }
        if (lane == 63) wt4[wid] = s;
        __syncthreads();
        int wo = 0;
#pragma unroll
        for (int j = 0; j < 4; j++) wo += (j < wid) ? wt4[j] : 0;
        fo[t] = wo + s - v;
    }
    __syncthreads();
    if (t < nloc) rowptr[node0 + t] = beg + fo[t];
    fh[t] = 0;
    __syncthreads();
    for (int e = beg + t; e < end; e += 256) {
        int v = ebuf[e];
        int d = v & (CBW - 1);
        int r = atomicAdd(&fh[d], 1);
        colidx[beg + fo[d] + r] = v >> 8;
    }
}

// ---------------- MFMA GEMM (fp16 input) + fused dots ----------------
__global__ __launch_bounds__(256) void k_gemm(const __half* __restrict__ X,
                                              const __half* __restrict__ Wt,
                                              const float* __restrict__ a_s,
                                              const float* __restrict__ a_d,
                                              __half* __restrict__ H,
                                              float* __restrict__ as_,
                                              float* __restrict__ ad_, int n) {
    const int t = threadIdx.x;
    const int wave = t >> 6, lane = t & 63;
    const int g = lane >> 4, c16 = lane & 15;
    const int row0 = blockIdx.x * 64 + wave * 16;

    half8 A[4];
    {
        int row = row0 + c16;
        int rc = (row < n) ? row : (n - 1);
        const __half* xp = &X[(size_t)rc * 128 + g * 8];
#pragma unroll
        for (int kc = 0; kc < 4; kc++) A[kc] = *(const half8*)(xp + kc * 32);
    }
    f32x4 acc[8];
#pragma unroll
    for (int ct = 0; ct < 8; ct++) acc[ct] = (f32x4){0.f, 0.f, 0.f, 0.f};
#pragma unroll
    for (int ct = 0; ct < 8; ct++) {
        const __half* wp = &Wt[(ct * 16 + c16) * 128 + g * 8];
#pragma unroll
        for (int kc = 0; kc < 4; kc++) {
            half8 b = *(const half8*)(wp + kc * 32);
            acc[ct] = __builtin_amdgcn_mfma_f32_16x16x32_f16(A[kc], b, acc[ct], 0, 0, 0);
        }
    }
    float asv[8], adv[8];
#pragma unroll
    for (int ct = 0; ct < 8; ct++) {
        asv[ct] = a_s[ct * 16 + c16];
        adv[ct] = a_d[ct * 16 + c16];
    }
#pragma unroll
    for (int r = 0; r < 4; r++) {
        const int row = row0 + g * 4 + r;
        float vs = 0.f, vd = 0.f;
#pragma unroll
        for (int ct = 0; ct < 8; ct++) {
            float v = acc[ct][r];
            vs += v * asv[ct];
            vd += v * adv[ct];
            if (row < n) H[(size_t)row * 128 + ct * 16 + c16] = __float2half(v);
        }
#pragma unroll
        for (int off = 8; off; off >>= 1) {
            vs += __shfl_xor(vs, off, 16);
            vd += __shfl_xor(vd, off, 16);
        }
        if (c16 == 0 && row < n) { as_[row] = vs; ad_[row] = vd; }
    }
}

// ---------------- fused softmax + aggregation (LDS-routed (off,w) pairs) ----------------
// Superstep of 64 edges: phase A — each lane owns one edge (coalesced colidx,
// ONE exp per edge, w=0 invalid), writes {src<<8, w} int2 to per-wave LDS slab.
// Phase B — each quarter-wave reads its group's pair with one broadcast
// ds_read_b64 (no shuffle, no decode) then 16-lane uint4 H-row load + fma_mix.
// DS-pipe is in-order per wave => no barrier needed (per-wave private slab).
// End-normalization exact (softmax shift-invariance; logits bounded).
__device__ __forceinline__ void fmix8(float* acc, uint4 hv, float w) {
    union { uint4 u; _Float16 h[8]; } c;
    c.u = hv;
#pragma unroll
    for (int j = 0; j < 8; j++) acc[j] += w * (float)c.h[j];
}

__global__ __launch_bounds__(256) void k_aggr(const __half* __restrict__ H,
                                              const float* __restrict__ as_,
                                              const float* __restrict__ ad_,
                                              const int* __restrict__ rowptr,
                                              const int* __restrict__ colidx,
                                              const float* __restrict__ bias,
                                              float* __restrict__ outf,
                                              __half* __restrict__ outh,
                                              int n, int mode) {   // mode1: relu+fp16 out
    __shared__ int2 pr[4][64];
    const int wid = threadIdx.x >> 6;
    const int lane = threadIdx.x & 63;
    const int node = blockIdx.x * 4 + wid;
    if (node >= n) return;
    const int q = lane >> 4;
    const int boff = (lane & 15) * 16;
    const char* Hb = (const char*)H + boff;
    const float adn = ad_[node];
    float sp = 0.f;
    float acc[8] = {0.f, 0.f, 0.f, 0.f, 0.f, 0.f, 0.f, 0.f};
    const int beg = rowptr[node], end = rowptr[node + 1];

    {   // self loop
        float e = as_[node] + adn;
        e = (e > 0.f) ? e : 0.2f * e;
        const float w = __expf(e);
        if (lane == 63) sp += w;
        if (q == 3) {
            const uint4 hv = *(const uint4*)(Hb + ((unsigned)node << 8));
            fmix8(acc, hv, w);
        }
    }

    for (int it = beg; it < end; it += 64) {
        const int idx = it + lane;
        const bool valid = idx < end;
        const int sl = colidx[valid ? idx : (end - 1)];
        float e = as_[sl] + adn;
        e = (e > 0.f) ? e : 0.2f * e;
        const float w = valid ? __expf(e) : 0.f;
        sp += w;
        pr[wid][lane] = make_int2((int)((unsigned)sl << 8), __float_as_int(w));
        int m = end - it; if (m > 64) m = 64;
        const int iters = (m + 3) >> 2;
        int slot = q;
#pragma unroll 4
        for (int g = 0; g < iters; ++g) {
            const int2 p = pr[wid][slot];
            const float wg = __int_as_float(p.y);
            const uint4 hv = *(const uint4*)(Hb + (unsigned)p.x);
            fmix8(acc, hv, wg);
            slot += 4;
        }
    }

#pragma unroll
    for (int off = 1; off < 64; off <<= 1) sp += __shfl_xor(sp, off);
#pragma unroll
    for (int off = 16; off <= 32; off <<= 1) {
#pragma unroll
        for (int j = 0; j < 8; j++) acc[j] += __shfl_xor(acc[j], off);
    }
    if (q == 0) {
        const int f0 = boff >> 1;
        const float inv = 1.f / sp;
        float o[8];
        const float4 b0 = *(const float4*)&bias[f0];
        const float4 b1 = *(const float4*)&bias[f0 + 4];
        o[0] = acc[0] * inv + b0.x; o[1] = acc[1] * inv + b0.y;
        o[2] = acc[2] * inv + b0.z; o[3] = acc[3] * inv + b0.w;
        o[4] = acc[4] * inv + b1.x; o[5] = acc[5] * inv + b1.y;
        o[6] = acc[6] * inv + b1.z; o[7] = acc[7] * inv + b1.w;
        if (mode == 1) {
#pragma unroll
            for (int j = 0; j < 8; j++) o[j] = fmaxf(o[j], 0.f);
            union { __half2 h2[4]; uint4 u; } pkk;
            pkk.h2[0] = __floats2half2_rn(o[0], o[1]);
            pkk.h2[1] = __floats2half2_rn(o[2], o[3]);
            pkk.h2[2] = __floats2half2_rn(o[4], o[5]);
            pkk.h2[3] = __floats2half2_rn(o[6], o[7]);
            *(uint4*)&outh[(size_t)node * 128 + f0] = pkk.u;
        } else {
            *(float4*)&outf[(size_t)node * 128 + f0] = make_float4(o[0], o[1], o[2], o[3]);
            *(float4*)&outf[(size_t)node * 128 + f0 + 4] = make_float4(o[4], o[5], o[6], o[7]);
        }
    }
}

extern "C" void kernel_launch(void* const* d_in, const int* in_sizes, int n_in,
                              void* d_out, int out_size, void* d_ws, size_t ws_size,
                              hipStream_t stream) {
    const float* x   = (const float*)d_in[0];
    const int*   ei  = (const int*)d_in[1];
    const float* W1  = (const float*)d_in[2];
    const float* a1s = (const float*)d_in[3];
    const float* a1d = (const float*)d_in[4];
    const float* b1  = (const float*)d_in[5];
    const float* W2  = (const float*)d_in[6];
    const float* a2s = (const float*)d_in[7];
    const float* a2d = (const float*)d_in[8];
    const float* b2  = (const float*)d_in[9];
    float* dout = (float*)d_out;

    const int n = in_sizes[0] / FD;          // 50000
    const int E = in_sizes[1] / 2;           // 1600000
    const int* src = ei;
    const int* dst = ei + E;
    const int NB = (n + CBW - 1) / CBW;      // 196 coarse buckets

    // workspace layout
    // buf0 (12.8 MB) time-shared: ebuf (CSR build) -> Y16 (layer1 output)
    char* base = (char*)d_ws;
    __half* buf0  = (__half*)base;                    // n*128 halves
    int*    ebuf  = (int*)base;                       // E ints (6.4 MB), aliases buf0
    __half* H     = (__half*)(base + (size_t)n * FD * sizeof(__half));
    float* as_    = (float*)((char*)H + (size_t)n * FD * sizeof(__half));
    float* ad_    = as_ + n;
    int*   rowptr = (int*)(ad_ + n);         // n+1
    int*   ccnt   = rowptr + (n + 1);        // NB
    int*   cbase  = ccnt + NB;               // NB+1
    int*   ccur   = cbase + NB + 1;          // NB
    int*   colidx = ccur + NB;               // E
    size_t wt_off = (((size_t)((char*)(colidx + E) - base)) + 15) & ~(size_t)15;
    __half* Wt1h  = (__half*)(base + wt_off);         // 32 KB
    __half* Wt2h  = Wt1h + 128 * 128;                  // 32 KB

    const int gemm_grid = (n + 63) / 64;     // 782
    const int node_grid = (n + 3) / 4;       // 12500
    const int SCAT = 256;

    // ---- D0: zero coarse counts ----
    hipMemsetAsync(ccnt, 0, (size_t)NB * sizeof(int), stream);
    // ---- D1: coarse hist || weight transpose ----
    k_pre<<<258, 256, 0, stream>>>(dst, ccnt, E, NB, W1, W2, Wt1h, Wt2h);
    // ---- D2: scan ----
    k_cscan<<<1, 1024, 0, stream>>>(ccnt, cbase, ccur, NB, rowptr, n);
    // ---- D3: coarse scatter || layer-1 GEMM (reads fp32 x) ----
    k_mid<<<SCAT + gemm_grid, 256, 0, stream>>>(src, dst, ccur, ebuf, E, NB, SCAT,
                                                x, Wt1h, a1s, a1d, H, as_, ad_, n);
    // ---- D4: fine sort -> colidx/rowptr ----
    k_fine<<<NB, 256, 0, stream>>>(ebuf, cbase, rowptr, colidx, n);
    // ---- D5: layer-1 aggregate (relu, fp16 out into buf0; ebuf dead) ----
    k_aggr<<<node_grid, 256, 0, stream>>>(H, as_, ad_, rowptr, colidx, b1,
                                          nullptr, buf0, n, 1);
    // ---- D6: layer-2 GEMM (fp16 input) ----
    k_gemm<<<gemm_grid, 256, 0, stream>>>(buf0, Wt2h, a2s, a2d, H, as_, ad_, n);
    // ---- D7: layer-2 aggregate (fp32 out) ----
    k_aggr<<<node_grid, 256, 0, stream>>>(H, as_, ad_, rowptr, colidx, b2,
                                          dout, nullptr, n, 0);
}